// Round 13
// baseline (32544.717 us; speedup 1.0000x reference)
//
#include <hip/hip_runtime.h>
#include <cstddef>

#define HID   256
#define CTXD  128
#define QDIM  128
#define VDNUM 33

typedef float  float4e __attribute__((ext_vector_type(4)));
typedef unsigned int uint4e __attribute__((ext_vector_type(4)));
typedef unsigned int uint2e __attribute__((ext_vector_type(2)));
typedef _Float16 half2e __attribute__((ext_vector_type(2)));

__device__ __forceinline__ float sigf(float x) { return 1.f / (1.f + expf(-x)); }

union H8 { uint4e u; half2e d[4]; _Float16 h[8]; };
union H4 { uint2e u; _Float16 h[4]; };

struct P {
    const int*   seqs;
    const float* key; const float* val; const float* embed;
    const float* Wih0; const float* Whh0; const float* bih0; const float* bhh0;
    const float* Wih1; const float* Whh1; const float* bih1; const float* bhh1;
    const float* Wih2; const float* Whh2; const float* bih2; const float* bhh2;
    const float* Wq;  const float* bq;
    const float* Ws1; const float* bs1;
    const float* Ws2; const float* bs2;
    const float* h0; const float* c0; const float* con;
    unsigned short* WH0; unsigned short* WH1; unsigned short* WH2;  // fp16 LSTM weights
    unsigned short* Ws1h;                                           // fp16 MLP1 weights
    float* bsum; float* WqT4; float* Ws2T; float* Ep;
    unsigned short* keyh; unsigned short* valh;                     // fp16 key/val copies
    int dokv;
    float* outS; float* outP;
    int S, T;
};

// ---------------------------------------------------------------------------
// One-time repack (every call, deterministic). Layouts identical to round 10.
// ---------------------------------------------------------------------------
__global__ void prep(P p)
{
    const int stride = gridDim.x * blockDim.x;
    const int i0 = blockIdx.x * blockDim.x + threadIdx.x;
    const int T = p.T;

    // Ep[c][r] = sum_k embed[c][k] * Wih0[r][k], k<256 (exact fp32)
    for (int z = i0; z < VDNUM * 1024; z += stride) {
        int c = z >> 10, r = z & 1023;
        const float* w = p.Wih0 + (size_t)r * 384;
        const float* e = p.embed + c * HID;
        float a = 0.f;
        #pragma unroll 8
        for (int k = 0; k < HID; ++k) a += e[k] * w[k];
        p.Ep[z] = a;
    }

    _Float16* w0 = (_Float16*)p.WH0;
    for (int z = i0; z < 48 * 8192; z += stride) {           // L0: K=384 = [ctx|h]
        int c = z >> 13, rem = z & 8191, r = rem >> 3, j = rem & 7;
        int k = c * 8 + j;
        float v = (k < 128) ? p.Wih0[(size_t)r * 384 + 256 + k]
                            : p.Whh0[(size_t)r * 256 + (k - 128)];
        w0[z] = (_Float16)v;
    }
    _Float16* w1 = (_Float16*)p.WH1;
    _Float16* w2 = (_Float16*)p.WH2;
    for (int z = i0; z < 64 * 8192; z += stride) {           // L1,L2: K=512
        int c = z >> 13, rem = z & 8191, r = rem >> 3, j = rem & 7;
        int k = c * 8 + j;
        w1[z] = (_Float16)((k < 256) ? p.Wih1[(size_t)r * 256 + k]
                                     : p.Whh1[(size_t)r * 256 + (k - 256)]);
        w2[z] = (_Float16)((k < 256) ? p.Wih2[(size_t)r * 256 + k]
                                     : p.Whh2[(size_t)r * 256 + (k - 256)]);
    }
    _Float16* ws1 = (_Float16*)p.Ws1h;
    for (int z = i0; z < 48 * 2048; z += stride) {           // Ws1: [256 j][384 k]
        int c = z >> 11, rem = z & 2047, j = rem >> 3, lane = rem & 7;
        int k = c * 8 + lane;
        ws1[z] = (_Float16)p.Ws1[(size_t)j * 384 + k];
    }
    for (int z = i0; z < 3072; z += stride) {                // bih+bhh fused
        int l = z >> 10, r = z & 1023;
        const float* bi = l == 0 ? p.bih0 : l == 1 ? p.bih1 : p.bih2;
        const float* bh = l == 0 ? p.bhh0 : l == 1 ? p.bhh1 : p.bhh2;
        p.bsum[z] = bi[r] + bh[r];
    }
    for (int z = i0; z < 256 * 128; z += stride) {           // WqT4 [k4][128][4] fp32
        int k = z >> 7, q = z & 127;
        p.WqT4[((size_t)(k >> 2) * 128 + q) * 4 + (k & 3)] = p.Wq[(size_t)q * HID + k];
    }
    for (int z = i0; z < 256 * VDNUM; z += stride) {         // Ws2T [k][33] fp32
        int k = z / VDNUM, v = z - k * VDNUM;
        p.Ws2T[(size_t)k * VDNUM + v] = p.Ws2[(size_t)v * HID + k];
    }
    if (p.dokv) {
        _Float16* kh = (_Float16*)p.keyh;
        _Float16* vh = (_Float16*)p.valh;
        const int NKV = 64 * QDIM * T;
        for (int z = i0; z < NKV; z += stride) kh[z] = (_Float16)p.key[z];
        for (int z = i0; z < NKV; z += stride) vh[z] = (_Float16)p.val[z];
    }
}

#define FD(acc, wd, xv) acc = __builtin_amdgcn_fdot2(wd, xv, acc, false);

// ---------------------------------------------------------------------------
// LSTM matvec via v_dot2_f32_f16, inside round 10's PROVEN depth-12 pipeline
// (A,B,C live 4-chunk batches + distance-3 prefetch, rotation movs). 12 sets
// = 48 weight VGPRs — fits without spill (round-11 lesson: 16 sets spilled
// to scratch, +47 MB/step HBM traffic). x is fp16 in LDS (broadcast reads).
// ---------------------------------------------------------------------------
template<int NCH>   // multiple of 4: 48 (L0) or 64 (L1/L2)
__device__ __forceinline__ float matvec_dot2(const unsigned short* W, int tid, const _Float16* x)
{
    const uint4e* w = (const uint4e*)W + tid;     // chunk stride = 1024 uint4e
    H8 A0, A1, A2, A3, B0, B1, B2, B3, C0, C1, C2, C3;
    A0.u = w[0];    A1.u = w[1024]; A2.u = w[2048];  A3.u = w[3072];
    B0.u = w[4096]; B1.u = w[5120]; B2.u = w[6144];  B3.u = w[7168];
    C0.u = w[8192]; C1.u = w[9216]; C2.u = w[10240]; C3.u = w[11264];
    float a0 = 0.f, a1 = 0.f;
    for (int c = 0; c < NCH; c += 4) {
        H8 N0, N1, N2, N3;
        const size_t base = (size_t)(c + 12) * 1024;   // pad chunks absorb overrun
        N0.u = w[base]; N1.u = w[base + 1024]; N2.u = w[base + 2048]; N3.u = w[base + 3072];
        const half2e* xx = (const half2e*)(x + c * 8);
        FD(a0, A0.d[0], xx[0])  FD(a1, A0.d[1], xx[1])
        FD(a0, A0.d[2], xx[2])  FD(a1, A0.d[3], xx[3])
        FD(a0, A1.d[0], xx[4])  FD(a1, A1.d[1], xx[5])
        FD(a0, A1.d[2], xx[6])  FD(a1, A1.d[3], xx[7])
        FD(a0, A2.d[0], xx[8])  FD(a1, A2.d[1], xx[9])
        FD(a0, A2.d[2], xx[10]) FD(a1, A2.d[3], xx[11])
        FD(a0, A3.d[0], xx[12]) FD(a1, A3.d[1], xx[13])
        FD(a0, A3.d[2], xx[14]) FD(a1, A3.d[3], xx[15])
        A0 = B0; A1 = B1; A2 = B2; A3 = B3;
        B0 = C0; B1 = C1; B2 = C2; B3 = C3;
        C0 = N0; C1 = N1; C2 = N2; C3 = N3;
    }
    return a0 + a1;
}

// ---------------------------------------------------------------------------
// Persistent per-batch-element kernel: 64 blocks x 1024 threads, zero
// device-scope sync. fp16 weights AND fp16 activations (dot2 operands);
// cell state c and all softmax/score math stay fp32.
// ---------------------------------------------------------------------------
template<bool KV16>
__global__ __launch_bounds__(1024, 4) void speller(P p)
{
    __shared__ float h[3][HID], c[3][HID], ctx[CTXD];
    __shared__ __align__(16) _Float16 xh0h[384];   // L0 input [ctx|h0] fp16
    __shared__ __align__(16) _Float16 xh12h[512];  // L1/L2 input fp16
    __shared__ __align__(16) _Float16 feath[384];  // MLP1 feat [h2|ctx] fp16
    __shared__ float gacc[1024];
    __shared__ float qry[QDIM];
    __shared__ float s_sc[2048];
    __shared__ float4e ep[4][256];
    __shared__ float red[16][CTXD];
    __shared__ float hid[HID];
    __shared__ float predp[VDNUM * 8];
    __shared__ float predv[VDNUM];
    __shared__ float wred[16];
    __shared__ float bcast;
    __shared__ int   chr;

    const int b   = blockIdx.x;
    const int tid = threadIdx.x;
    const int T   = p.T;
    const int T4  = T >> 2;
    const int n   = p.seqs[b];

    if (tid < HID) {
        #pragma unroll
        for (int l = 0; l < 3; ++l) { h[l][tid] = p.h0[l * HID + tid]; c[l][tid] = p.c0[l * HID + tid]; }
    }
    if (tid < CTXD) ctx[tid] = p.con[tid];
    if (tid == 0)   chr = 0;
    __syncthreads();

    for (int s = 0; s < p.S; ++s) {
        // ---- build L0 input (fp16): [ctx | h0_old]; embed part from Ep ----
        if (tid < 128)      xh0h[tid] = (_Float16)ctx[tid];
        else if (tid < 384) xh0h[tid] = (_Float16)h[0][tid - 128];
        __syncthreads();

        // ---- L0 (K=384, 48 chunks) + Ep lookup ----
        gacc[tid] = p.bsum[tid] + p.Ep[(size_t)chr * 1024 + tid]
                  + matvec_dot2<48>(p.WH0, tid, xh0h);
        __syncthreads();
        if (tid < HID) {   // gate order i,f,g,o
            float gi = gacc[tid], gf = gacc[256 + tid], gg = gacc[512 + tid], go = gacc[768 + tid];
            float cn = sigf(gf) * c[0][tid] + sigf(gi) * tanhf(gg);
            c[0][tid] = cn;
            float hn = sigf(go) * tanhf(cn);
            h[0][tid] = hn;
            xh12h[tid] = (_Float16)hn; xh12h[256 + tid] = (_Float16)h[1][tid];
        }
        __syncthreads();

        // ---- L1 (K=512, 64 chunks) ----
        gacc[tid] = p.bsum[1024 + tid] + matvec_dot2<64>(p.WH1, tid, xh12h);
        __syncthreads();
        if (tid < HID) {
            float gi = gacc[tid], gf = gacc[256 + tid], gg = gacc[512 + tid], go = gacc[768 + tid];
            float cn = sigf(gf) * c[1][tid] + sigf(gi) * tanhf(gg);
            c[1][tid] = cn;
            float hn = sigf(go) * tanhf(cn);
            h[1][tid] = hn;
            xh12h[tid] = (_Float16)hn; xh12h[256 + tid] = (_Float16)h[2][tid];
        }
        __syncthreads();

        // ---- L2 (K=512, 64 chunks) ----
        gacc[tid] = p.bsum[2048 + tid] + matvec_dot2<64>(p.WH2, tid, xh12h);
        __syncthreads();
        if (tid < HID) {
            float gi = gacc[tid], gf = gacc[256 + tid], gg = gacc[512 + tid], go = gacc[768 + tid];
            float cn = sigf(gf) * c[2][tid] + sigf(gi) * tanhf(gg);
            c[2][tid] = cn;
            h[2][tid] = sigf(go) * tanhf(cn);
        }
        __syncthreads();

        // ---- query = h2 @ Wq^T + bq (fp32 — kept full precision) ----
        {
            const int q = tid & 127, ch = tid >> 7;
            const float4e* w = (const float4e*)p.WqT4 + q;
            float a = 0;
            #pragma unroll
            for (int i = 0; i < 8; ++i) {
                int k4 = ch * 8 + i;
                float4e wv = w[(size_t)k4 * 128];
                const float* x = &h[2][k4 * 4];
                a += x[0] * wv.x + x[1] * wv.y + x[2] * wv.z + x[3] * wv.w;
            }
            gacc[ch * 128 + q] = a;
        }
        __syncthreads();
        if (tid < QDIM) {
            float a = p.bq[tid];
            #pragma unroll
            for (int i = 0; i < 8; ++i) a += gacc[i * 128 + tid];
            qry[tid] = a;
        }
        __syncthreads();

        // ---- energy: 2 passes over t-halves; thread = (t4 slot, q-group) ----
        {
            const int tl = tid & 255, qg = tid >> 8;
            #pragma unroll
            for (int half = 0; half < 2; ++half) {
                const int t0 = half << 10;
                float4e e = {0.f, 0.f, 0.f, 0.f};
                if (t0 < n) {
                    const int q0 = qg * 32;
                    if (KV16) {
                        const uint2e* k2 = (const uint2e*)p.keyh
                            + (((size_t)b * QDIM * T + t0) >> 2) + tl;
                        #pragma unroll 8
                        for (int qq = 0; qq < 32; ++qq) {
                            H4 kv; kv.u = k2[(size_t)(q0 + qq) * (T >> 2)];
                            float qv = qry[q0 + qq];
                            e.x += qv * (float)kv.h[0];
                            e.y += qv * (float)kv.h[1];
                            e.z += qv * (float)kv.h[2];
                            e.w += qv * (float)kv.h[3];
                        }
                    } else {
                        const float4e* k4 = (const float4e*)p.key + (size_t)b * QDIM * T4
                                          + (t0 >> 2) + tl;
                        #pragma unroll 8
                        for (int qq = 0; qq < 32; ++qq) {
                            float4e kv = k4[(size_t)(q0 + qq) * T4];
                            e += qry[q0 + qq] * kv;
                        }
                    }
                }
                ep[qg][tl] = e;
                __syncthreads();
                if (tid < 256 && t0 < n) {
                    float4e r = (ep[0][tid] + ep[1][tid]) + (ep[2][tid] + ep[3][tid]);
                    ((float4e*)s_sc)[(t0 >> 2) + tid] = r;
                }
                __syncthreads();
            }
        }

        // ---- max over t<n ----
        float m = -INFINITY;
        for (int t = tid; t < n; t += 1024) m = fmaxf(m, s_sc[t]);
        #pragma unroll
        for (int off = 32; off; off >>= 1) m = fmaxf(m, __shfl_xor(m, off));
        if ((tid & 63) == 0) wred[tid >> 6] = m;
        __syncthreads();
        if (tid == 0) {
            float r = wred[0];
            #pragma unroll
            for (int i = 1; i < 16; ++i) r = fmaxf(r, wred[i]);
            bcast = r;
        }
        __syncthreads();
        m = bcast;

        // ---- exp + sum ----
        float z = 0.f;
        for (int t = tid; t < T; t += 1024) {
            float pv = 0.f;
            if (t < n) { pv = expf(s_sc[t] - m); z += pv; }
            s_sc[t] = pv;
        }
        #pragma unroll
        for (int off = 32; off; off >>= 1) z += __shfl_xor(z, off);
        if ((tid & 63) == 0) wred[tid >> 6] = z;
        __syncthreads();
        if (tid == 0) {
            float r = 0.f;
            #pragma unroll
            for (int i = 0; i < 16; ++i) r += wred[i];
            bcast = r;
        }
        __syncthreads();
        const float Z = bcast;

        // ---- scores out ----
        float* so = p.outS + ((size_t)b * p.S + s) * T;
        for (int t = tid; t < T; t += 1024) {
            float sc = s_sc[t] / Z;
            s_sc[t] = sc;
            __builtin_nontemporal_store(sc, so + t);
        }
        __syncthreads();

        // ---- ctx = sum_{t<n} score[t] * val[b][t][:] ----
        {
            const int tg = tid >> 5, cq = tid & 31;
            float ax = 0, ay = 0, az = 0, aw = 0;
            if (KV16) {
                const uint2e* v2 = (const uint2e*)p.valh + (size_t)b * T * 32 + cq;
                #pragma unroll 4
                for (int t = tg; t < n; t += 32) {
                    float sv = s_sc[t];
                    H4 vv; vv.u = v2[(size_t)t * 32];
                    ax += sv * (float)vv.h[0]; ay += sv * (float)vv.h[1];
                    az += sv * (float)vv.h[2]; aw += sv * (float)vv.h[3];
                }
            } else {
                const float4e* v4 = (const float4e*)p.val + (size_t)b * T * 32 + cq;
                #pragma unroll 4
                for (int t = tg; t < n; t += 32) {
                    float   sv = s_sc[t];
                    float4e vv = v4[(size_t)t * 32];
                    ax += sv * vv.x; ay += sv * vv.y; az += sv * vv.z; aw += sv * vv.w;
                }
            }
            ax += __shfl_xor(ax, 32); ay += __shfl_xor(ay, 32);
            az += __shfl_xor(az, 32); aw += __shfl_xor(aw, 32);
            if ((tid & 63) < 32) {
                const int w = tid >> 6;
                red[w][cq * 4 + 0] = ax; red[w][cq * 4 + 1] = ay;
                red[w][cq * 4 + 2] = az; red[w][cq * 4 + 3] = aw;
            }
        }
        __syncthreads();
        if (tid < CTXD) {
            float a = 0.f;
            #pragma unroll
            for (int w = 0; w < 16; ++w) a += red[w][tid];
            ctx[tid] = a;
            feath[256 + tid] = (_Float16)a;        // feat = [h2 | ctx_new]
        }
        if (tid < HID) feath[tid] = (_Float16)h[2][tid];
        __syncthreads();

        // ---- MLP1: hid = relu(feat @ Ws1^T + bs1), dot2 (1 live set, safe) ----
        {
            const int j = tid & 255, ch = tid >> 8;
            const uint4e* w = (const uint4e*)p.Ws1h + (size_t)(ch * 12) * 256 + j;
            H8 cc; cc.u = w[0];
            float a0 = 0.f, a1 = 0.f;
            #pragma unroll 2
            for (int u = 0; u < 12; ++u) {
                H8 nx; nx.u = w[(size_t)(u + 1) * 256];   // pad chunk absorbs overrun
                const half2e* xx = (const half2e*)(feath + (ch * 12 + u) * 8);
                FD(a0, cc.d[0], xx[0]) FD(a1, cc.d[1], xx[1])
                FD(a0, cc.d[2], xx[2]) FD(a1, cc.d[3], xx[3])
                cc = nx;
            }
            gacc[ch * 256 + j] = a0 + a1;
        }
        __syncthreads();
        if (tid < HID)
            hid[tid] = fmaxf(p.bs1[tid] + ((gacc[tid] + gacc[256 + tid]) + (gacc[512 + tid] + gacc[768 + tid])), 0.f);
        __syncthreads();

        // ---- predict = hid @ Ws2^T + bs2 (fp32); argmax feedback ----
        if (tid < VDNUM * 8) {
            const int v = tid >> 3, oct = tid & 7;
            const float* w2 = p.Ws2T + (size_t)oct * 32 * VDNUM + v;
            float a = 0.f;
            #pragma unroll 8
            for (int k = 0; k < 32; ++k) a += hid[oct * 32 + k] * w2[(size_t)k * VDNUM];
            predp[v * 8 + oct] = a;
        }
        __syncthreads();
        if (tid < VDNUM) {
            float a = p.bs2[tid];
            #pragma unroll
            for (int o = 0; o < 8; ++o) a += predp[tid * 8 + o];
            __builtin_nontemporal_store(a, p.outP + ((size_t)b * p.S + s) * VDNUM + tid);
            predv[tid] = a;
        }
        __syncthreads();
        if (tid == 0) {   // first-occurrence argmax (strict >)
            int best = 0; float bv = predv[0];
            for (int v = 1; v < VDNUM; ++v) if (predv[v] > bv) { bv = predv[v]; best = v; }
            chr = best;
        }
        __syncthreads();
    }
}

extern "C" void kernel_launch(void* const* d_in, const int* in_sizes, int n_in,
                              void* d_out, int out_size, void* d_ws, size_t ws_size,
                              hipStream_t stream)
{
    P p;
    p.seqs  = (const int*)  d_in[0];
    p.key   = (const float*)d_in[1];
    p.val   = (const float*)d_in[2];
    p.embed = (const float*)d_in[4];
    p.Wih0  = (const float*)d_in[5];  p.Whh0 = (const float*)d_in[6];
    p.bih0  = (const float*)d_in[7];  p.bhh0 = (const float*)d_in[8];
    p.Wih1  = (const float*)d_in[9];  p.Whh1 = (const float*)d_in[10];
    p.bih1  = (const float*)d_in[11]; p.bhh1 = (const float*)d_in[12];
    p.Wih2  = (const float*)d_in[13]; p.Whh2 = (const float*)d_in[14];
    p.bih2  = (const float*)d_in[15]; p.bhh2 = (const float*)d_in[16];
    p.Wq    = (const float*)d_in[17]; p.bq   = (const float*)d_in[18];
    p.Ws1   = (const float*)d_in[19]; p.bs1  = (const float*)d_in[20];
    p.Ws2   = (const float*)d_in[21]; p.bs2  = (const float*)d_in[22];
    p.h0    = (const float*)d_in[23];
    p.c0    = (const float*)d_in[24];
    p.con   = (const float*)d_in[25];

    const int B = in_sizes[0];                  // 64
    p.T = in_sizes[1] / (B * QDIM);             // 2048
    p.S = in_sizes[3] / B;                      // 220

    // workspace layout (bytes; 16B-aligned) — identical to round 10
    char* ws = (char*)d_ws;
    p.WH0  = (unsigned short*)(ws + 0);          // 64 chunks  = 1,048,576 B
    p.WH1  = (unsigned short*)(ws + 1048576);    // 80 chunks  = 1,310,720 B
    p.WH2  = (unsigned short*)(ws + 2359296);    // 1,310,720 B
    p.Ws1h = (unsigned short*)(ws + 3670016);    //   200,704 B
    p.bsum = (float*)(ws + 3870720);             //    12,288 B
    p.WqT4 = (float*)(ws + 3883008);             //   131,072 B
    p.Ws2T = (float*)(ws + 4014080);             //    33,792 B
    p.Ep   = (float*)(ws + 4047872);             //   135,168 B  -> end 4,183,040

    const size_t kvBytes = (size_t)B * QDIM * p.T * 2;
    p.keyh = (unsigned short*)(ws + 4183040);
    p.valh = (unsigned short*)(ws + 4183040 + kvBytes);
    p.dokv = (ws_size >= 4183040 + 2 * kvBytes) ? 1 : 0;

    p.outS = (float*)d_out;
    p.outP = p.outS + (size_t)B * p.S * p.T;

    prep<<<1024, 256, 0, stream>>>(p);
    if (p.dokv) speller<true ><<<B, 1024, 0, stream>>>(p);
    else        speller<false><<<B, 1024, 0, stream>>>(p);
}

// Round 15
// 17884.821 us; speedup vs baseline: 1.8197x; 1.8197x over previous
//
#include <hip/hip_runtime.h>
#include <cstddef>

#define HID   256
#define CTXD  128
#define QDIM  128
#define VDNUM 33

typedef float  float4e __attribute__((ext_vector_type(4)));
typedef unsigned int uint4e __attribute__((ext_vector_type(4)));
typedef unsigned int uint2e __attribute__((ext_vector_type(2)));

__device__ __forceinline__ float sigf(float x) { return 1.f / (1.f + expf(-x)); }

union H8 { uint4e u; _Float16 h[8]; };
union H4 { uint2e u; _Float16 h[4]; };

struct P {
    const int*   seqs;
    const float* key; const float* val; const float* embed;
    const float* Wih0; const float* Whh0; const float* bih0; const float* bhh0;
    const float* Wih1; const float* Whh1; const float* bih1; const float* bhh1;
    const float* Wih2; const float* Whh2; const float* bih2; const float* bhh2;
    const float* Wq;  const float* bq;
    const float* Ws1; const float* bs1;
    const float* Ws2; const float* bs2;
    const float* h0; const float* c0; const float* con;
    unsigned short* WH0; unsigned short* WH1; unsigned short* WH2;  // fp16 LSTM weights
    unsigned short* Ws1h;                                           // fp16 MLP1 weights
    float* bsum; float* WqT4; float* Ws2T; float* Ep;
    unsigned short* keyh; unsigned short* valh;                     // fp16 key/val copies
    int dokv;
    float* outS; float* outP;
    int S, T;
};

// ---------------------------------------------------------------------------
// One-time repack (every call, deterministic): fp16 LSTM/MLP weights in
// chunk-of-8 layout (pad chunks absorb depth-12 prefetch overrun), Ep embed
// fold (exact fp32), and — when workspace allows — fp16 copies of key/val in
// the SAME layout as the fp32 originals (halves bytes AND 64B-line count of
// the per-step L3 stream, which is per-CU concurrency-limited).
// ---------------------------------------------------------------------------
__global__ void prep(P p)
{
    const int stride = gridDim.x * blockDim.x;
    const int i0 = blockIdx.x * blockDim.x + threadIdx.x;
    const int T = p.T;

    // Ep[c][r] = sum_k embed[c][k] * Wih0[r][k], k<256 (exact fp32)
    for (int z = i0; z < VDNUM * 1024; z += stride) {
        int c = z >> 10, r = z & 1023;
        const float* w = p.Wih0 + (size_t)r * 384;
        const float* e = p.embed + c * HID;
        float a = 0.f;
        #pragma unroll 8
        for (int k = 0; k < HID; ++k) a += e[k] * w[k];
        p.Ep[z] = a;
    }

    _Float16* w0 = (_Float16*)p.WH0;
    for (int z = i0; z < 48 * 8192; z += stride) {           // L0: K=384 = [ctx|h]
        int c = z >> 13, rem = z & 8191, r = rem >> 3, j = rem & 7;
        int k = c * 8 + j;
        float v = (k < 128) ? p.Wih0[(size_t)r * 384 + 256 + k]
                            : p.Whh0[(size_t)r * 256 + (k - 128)];
        w0[z] = (_Float16)v;
    }
    _Float16* w1 = (_Float16*)p.WH1;
    _Float16* w2 = (_Float16*)p.WH2;
    for (int z = i0; z < 64 * 8192; z += stride) {           // L1,L2: K=512
        int c = z >> 13, rem = z & 8191, r = rem >> 3, j = rem & 7;
        int k = c * 8 + j;
        w1[z] = (_Float16)((k < 256) ? p.Wih1[(size_t)r * 256 + k]
                                     : p.Whh1[(size_t)r * 256 + (k - 256)]);
        w2[z] = (_Float16)((k < 256) ? p.Wih2[(size_t)r * 256 + k]
                                     : p.Whh2[(size_t)r * 256 + (k - 256)]);
    }
    _Float16* ws1 = (_Float16*)p.Ws1h;
    for (int z = i0; z < 48 * 2048; z += stride) {           // Ws1: [256 j][384 k]
        int c = z >> 11, rem = z & 2047, j = rem >> 3, lane = rem & 7;
        int k = c * 8 + lane;
        ws1[z] = (_Float16)p.Ws1[(size_t)j * 384 + k];
    }
    for (int z = i0; z < 3072; z += stride) {                // bih+bhh fused
        int l = z >> 10, r = z & 1023;
        const float* bi = l == 0 ? p.bih0 : l == 1 ? p.bih1 : p.bih2;
        const float* bh = l == 0 ? p.bhh0 : l == 1 ? p.bhh1 : p.bhh2;
        p.bsum[z] = bi[r] + bh[r];
    }
    for (int z = i0; z < 256 * 128; z += stride) {           // WqT4 [k4][128][4] fp32
        int k = z >> 7, q = z & 127;
        p.WqT4[((size_t)(k >> 2) * 128 + q) * 4 + (k & 3)] = p.Wq[(size_t)q * HID + k];
    }
    for (int z = i0; z < 256 * VDNUM; z += stride) {         // Ws2T [k][33] fp32
        int k = z / VDNUM, v = z - k * VDNUM;
        p.Ws2T[(size_t)k * VDNUM + v] = p.Ws2[(size_t)v * HID + k];
    }
    if (p.dokv) {
        _Float16* kh = (_Float16*)p.keyh;
        _Float16* vh = (_Float16*)p.valh;
        const int NKV = 64 * QDIM * T;                       // 33.5M each
        for (int z = i0; z < NKV; z += stride) kh[z] = (_Float16)p.key[z];
        for (int z = i0; z < NKV; z += stride) vh[z] = (_Float16)p.val[z];
    }
}

#define DOT8(C, xx, off) \
    a0 += (float)C.h[0] * xx[off+0] + (float)C.h[1] * xx[off+1] \
        + (float)C.h[2] * xx[off+2] + (float)C.h[3] * xx[off+3]; \
    a1 += (float)C.h[4] * xx[off+4] + (float)C.h[5] * xx[off+5] \
        + (float)C.h[6] * xx[off+6] + (float)C.h[7] * xx[off+7];

// ---------------------------------------------------------------------------
// LSTM matvec: thread owns gate-row `tid`. Depth-12 chunk software pipeline
// (A,B,C live batches + distance-3 prefetch): 192 B/thread in flight.
// fma_mix precision: exact fp16->fp32 convert, fp32 multiply-accumulate —
// weight quantization is the only error source (proven class, rounds 7-10).
// ---------------------------------------------------------------------------
template<int NCH>
__device__ __forceinline__ float matvec_h8(const unsigned short* W, int tid, const float* x)
{
    const uint4e* w = (const uint4e*)W + tid;
    H8 A0, A1, A2, A3, B0, B1, B2, B3, C0, C1, C2, C3;
    A0.u = w[0];    A1.u = w[1024]; A2.u = w[2048];  A3.u = w[3072];
    B0.u = w[4096]; B1.u = w[5120]; B2.u = w[6144];  B3.u = w[7168];
    C0.u = w[8192]; C1.u = w[9216]; C2.u = w[10240]; C3.u = w[11264];
    float a0 = 0.f, a1 = 0.f;
    for (int c = 0; c < NCH; c += 4) {
        H8 N0, N1, N2, N3;
        const size_t base = (size_t)(c + 12) * 1024;
        N0.u = w[base]; N1.u = w[base + 1024]; N2.u = w[base + 2048]; N3.u = w[base + 3072];
        const float* xx = x + c * 8;
        DOT8(A0, xx, 0) DOT8(A1, xx, 8) DOT8(A2, xx, 16) DOT8(A3, xx, 24)
        A0 = B0; A1 = B1; A2 = B2; A3 = B3;
        B0 = C0; B1 = C1; B2 = C2; B3 = C3;
        C0 = N0; C1 = N1; C2 = N2; C3 = N3;
    }
    return a0 + a1;
}

// ---------------------------------------------------------------------------
// Persistent per-batch-element kernel: 64 blocks x 1024 threads, zero
// device-scope sync. KV16: key/val read as fp16 (converted in-register;
// summation order identical to fp32 path — only operand quantization changes).
// ---------------------------------------------------------------------------
template<bool KV16>
__global__ __launch_bounds__(1024, 4) void speller(P p)
{
    __shared__ float h[3][HID], c[3][HID], ctx[CTXD];
    __shared__ float xh0[512];
    __shared__ float xh12[512];
    __shared__ float gacc[1024];
    __shared__ float qry[QDIM];
    __shared__ float s_sc[2048];
    __shared__ float4e ep[4][256];
    __shared__ float red[16][CTXD];
    __shared__ float hid[HID];
    __shared__ float predp[VDNUM * 8];
    __shared__ float predv[VDNUM];
    __shared__ float wred[16];
    __shared__ float bcast;
    __shared__ int   chr;

    const int b   = blockIdx.x;
    const int tid = threadIdx.x;
    const int T   = p.T;
    const int T4  = T >> 2;
    const int n   = p.seqs[b];

    if (tid < HID) {
        #pragma unroll
        for (int l = 0; l < 3; ++l) { h[l][tid] = p.h0[l * HID + tid]; c[l][tid] = p.c0[l * HID + tid]; }
    }
    if (tid < CTXD) ctx[tid] = p.con[tid];
    if (tid == 0)   chr = 0;
    __syncthreads();

    for (int s = 0; s < p.S; ++s) {
        // ---- build L0 input: [ctx | h0_old] (embed part from Ep) ----
        if (tid < 128)      xh0[tid] = ctx[tid];
        else if (tid < 384) xh0[tid] = h[0][tid - 128];
        __syncthreads();

        // ---- L0 (K=384) + Ep lookup ----
        gacc[tid] = p.bsum[tid] + p.Ep[(size_t)chr * 1024 + tid]
                  + matvec_h8<48>(p.WH0, tid, xh0);
        __syncthreads();
        if (tid < HID) {
            float gi = gacc[tid], gf = gacc[256 + tid], gg = gacc[512 + tid], go = gacc[768 + tid];
            float cn = sigf(gf) * c[0][tid] + sigf(gi) * tanhf(gg);
            c[0][tid] = cn;
            float hn = sigf(go) * tanhf(cn);
            h[0][tid] = hn;
            xh12[tid] = hn; xh12[256 + tid] = h[1][tid];
        }
        __syncthreads();

        // ---- L1 (K=512) ----
        gacc[tid] = p.bsum[1024 + tid] + matvec_h8<64>(p.WH1, tid, xh12);
        __syncthreads();
        if (tid < HID) {
            float gi = gacc[tid], gf = gacc[256 + tid], gg = gacc[512 + tid], go = gacc[768 + tid];
            float cn = sigf(gf) * c[1][tid] + sigf(gi) * tanhf(gg);
            c[1][tid] = cn;
            float hn = sigf(go) * tanhf(cn);
            h[1][tid] = hn;
            xh12[tid] = hn; xh12[256 + tid] = h[2][tid];
        }
        __syncthreads();

        // ---- L2 (K=512) ----
        gacc[tid] = p.bsum[2048 + tid] + matvec_h8<64>(p.WH2, tid, xh12);
        __syncthreads();
        if (tid < HID) {
            float gi = gacc[tid], gf = gacc[256 + tid], gg = gacc[512 + tid], go = gacc[768 + tid];
            float cn = sigf(gf) * c[2][tid] + sigf(gi) * tanhf(gg);
            c[2][tid] = cn;
            h[2][tid] = sigf(go) * tanhf(cn);
        }
        __syncthreads();

        // ---- query = h2 @ Wq^T + bq ----
        {
            const int q = tid & 127, ch = tid >> 7;
            const float4e* w = (const float4e*)p.WqT4 + q;
            float a = 0;
            #pragma unroll
            for (int i = 0; i < 8; ++i) {
                int k4 = ch * 8 + i;
                float4e wv = w[(size_t)k4 * 128];
                const float* x = &h[2][k4 * 4];
                a += x[0] * wv.x + x[1] * wv.y + x[2] * wv.z + x[3] * wv.w;
            }
            gacc[ch * 128 + q] = a;
        }
        __syncthreads();
        if (tid < QDIM) {
            float a = p.bq[tid];
            #pragma unroll
            for (int i = 0; i < 8; ++i) a += gacc[i * 128 + tid];
            qry[tid] = a;
        }
        __syncthreads();

        // ---- energy: 2 passes over t-halves; thread = (t4 slot, q-group) ----
        {
            const int tl = tid & 255, qg = tid >> 8;
            #pragma unroll
            for (int half = 0; half < 2; ++half) {
                const int t0 = half << 10;
                float4e e = {0.f, 0.f, 0.f, 0.f};
                if (t0 < n) {
                    const int q0 = qg * 32;
                    if (KV16) {
                        const uint2e* k2 = (const uint2e*)p.keyh
                            + (((size_t)b * QDIM * T + t0) >> 2) + tl;
                        #pragma unroll 8
                        for (int qq = 0; qq < 32; ++qq) {
                            H4 kv; kv.u = k2[(size_t)(q0 + qq) * (T >> 2)];
                            float qv = qry[q0 + qq];
                            e.x += qv * (float)kv.h[0];
                            e.y += qv * (float)kv.h[1];
                            e.z += qv * (float)kv.h[2];
                            e.w += qv * (float)kv.h[3];
                        }
                    } else {
                        const float4e* k4 = (const float4e*)p.key + (size_t)b * QDIM * T4
                                          + (t0 >> 2) + tl;
                        #pragma unroll 8
                        for (int qq = 0; qq < 32; ++qq) {
                            float4e kv = k4[(size_t)(q0 + qq) * T4];
                            e += qry[q0 + qq] * kv;
                        }
                    }
                }
                ep[qg][tl] = e;
                __syncthreads();
                if (tid < 256 && t0 < n) {
                    float4e r = (ep[0][tid] + ep[1][tid]) + (ep[2][tid] + ep[3][tid]);
                    ((float4e*)s_sc)[(t0 >> 2) + tid] = r;
                }
                __syncthreads();
            }
        }

        // ---- max over t<n ----
        float m = -INFINITY;
        for (int t = tid; t < n; t += 1024) m = fmaxf(m, s_sc[t]);
        #pragma unroll
        for (int off = 32; off; off >>= 1) m = fmaxf(m, __shfl_xor(m, off));
        if ((tid & 63) == 0) wred[tid >> 6] = m;
        __syncthreads();
        if (tid == 0) {
            float r = wred[0];
            #pragma unroll
            for (int i = 1; i < 16; ++i) r = fmaxf(r, wred[i]);
            bcast = r;
        }
        __syncthreads();
        m = bcast;

        // ---- exp + sum ----
        float z = 0.f;
        for (int t = tid; t < T; t += 1024) {
            float pv = 0.f;
            if (t < n) { pv = expf(s_sc[t] - m); z += pv; }
            s_sc[t] = pv;
        }
        #pragma unroll
        for (int off = 32; off; off >>= 1) z += __shfl_xor(z, off);
        if ((tid & 63) == 0) wred[tid >> 6] = z;
        __syncthreads();
        if (tid == 0) {
            float r = 0.f;
            #pragma unroll
            for (int i = 0; i < 16; ++i) r += wred[i];
            bcast = r;
        }
        __syncthreads();
        const float Z = bcast;

        // ---- scores out ----
        float* so = p.outS + ((size_t)b * p.S + s) * T;
        for (int t = tid; t < T; t += 1024) {
            float sc = s_sc[t] / Z;
            s_sc[t] = sc;
            __builtin_nontemporal_store(sc, so + t);
        }
        __syncthreads();

        // ---- ctx = sum_{t<n} score[t] * val[b][t][:] ----
        {
            const int tg = tid >> 5, cq = tid & 31;
            float ax = 0, ay = 0, az = 0, aw = 0;
            if (KV16) {
                const uint2e* v2 = (const uint2e*)p.valh + (size_t)b * T * 32 + cq;
                #pragma unroll 4
                for (int t = tg; t < n; t += 32) {
                    float sv = s_sc[t];
                    H4 vv; vv.u = v2[(size_t)t * 32];
                    ax += sv * (float)vv.h[0]; ay += sv * (float)vv.h[1];
                    az += sv * (float)vv.h[2]; aw += sv * (float)vv.h[3];
                }
            } else {
                const float4e* v4 = (const float4e*)p.val + (size_t)b * T * 32 + cq;
                #pragma unroll 4
                for (int t = tg; t < n; t += 32) {
                    float   sv = s_sc[t];
                    float4e vv = v4[(size_t)t * 32];
                    ax += sv * vv.x; ay += sv * vv.y; az += sv * vv.z; aw += sv * vv.w;
                }
            }
            ax += __shfl_xor(ax, 32); ay += __shfl_xor(ay, 32);
            az += __shfl_xor(az, 32); aw += __shfl_xor(aw, 32);
            if ((tid & 63) < 32) {
                const int w = tid >> 6;
                red[w][cq * 4 + 0] = ax; red[w][cq * 4 + 1] = ay;
                red[w][cq * 4 + 2] = az; red[w][cq * 4 + 3] = aw;
            }
        }
        __syncthreads();
        if (tid < CTXD) {
            float a = 0.f;
            #pragma unroll
            for (int w = 0; w < 16; ++w) a += red[w][tid];
            ctx[tid] = a;
            xh0[256 + tid] = a;
        }
        if (tid < HID) xh0[tid] = h[2][tid];
        __syncthreads();

        // ---- MLP1: hid = relu(feat @ Ws1^T + bs1) ----
        {
            const int j = tid & 255, ch = tid >> 8;
            const uint4e* w = (const uint4e*)p.Ws1h + (size_t)(ch * 12) * 256 + j;
            H8 cc; cc.u = w[0];
            float a = 0.f;
            #pragma unroll 2
            for (int u = 0; u < 12; ++u) {
                H8 nx; nx.u = w[(size_t)(u + 1) * 256];
                const float* x = xh0 + (ch * 12 + u) * 8;
                a += (float)cc.h[0] * x[0] + (float)cc.h[1] * x[1]
                   + (float)cc.h[2] * x[2] + (float)cc.h[3] * x[3]
                   + (float)cc.h[4] * x[4] + (float)cc.h[5] * x[5]
                   + (float)cc.h[6] * x[6] + (float)cc.h[7] * x[7];
                cc = nx;
            }
            gacc[ch * 256 + j] = a;
        }
        __syncthreads();
        if (tid < HID)
            hid[tid] = fmaxf(p.bs1[tid] + ((gacc[tid] + gacc[256 + tid]) + (gacc[512 + tid] + gacc[768 + tid])), 0.f);
        __syncthreads();

        // ---- predict + argmax feedback ----
        if (tid < VDNUM * 8) {
            const int v = tid >> 3, oct = tid & 7;
            const float* w2 = p.Ws2T + (size_t)oct * 32 * VDNUM + v;
            float a = 0.f;
            #pragma unroll 8
            for (int k = 0; k < 32; ++k) a += hid[oct * 32 + k] * w2[(size_t)k * VDNUM];
            predp[v * 8 + oct] = a;
        }
        __syncthreads();
        if (tid < VDNUM) {
            float a = p.bs2[tid];
            #pragma unroll
            for (int o = 0; o < 8; ++o) a += predp[tid * 8 + o];
            __builtin_nontemporal_store(a, p.outP + ((size_t)b * p.S + s) * VDNUM + tid);
            predv[tid] = a;
        }
        __syncthreads();
        if (tid == 0) {   // first-occurrence argmax (strict >)
            int best = 0; float bv = predv[0];
            for (int v = 1; v < VDNUM; ++v) if (predv[v] > bv) { bv = predv[v]; best = v; }
            chr = best;
        }
        __syncthreads();
    }
}

extern "C" void kernel_launch(void* const* d_in, const int* in_sizes, int n_in,
                              void* d_out, int out_size, void* d_ws, size_t ws_size,
                              hipStream_t stream)
{
    P p;
    p.seqs  = (const int*)  d_in[0];
    p.key   = (const float*)d_in[1];
    p.val   = (const float*)d_in[2];
    p.embed = (const float*)d_in[4];
    p.Wih0  = (const float*)d_in[5];  p.Whh0 = (const float*)d_in[6];
    p.bih0  = (const float*)d_in[7];  p.bhh0 = (const float*)d_in[8];
    p.Wih1  = (const float*)d_in[9];  p.Whh1 = (const float*)d_in[10];
    p.bih1  = (const float*)d_in[11]; p.bhh1 = (const float*)d_in[12];
    p.Wih2  = (const float*)d_in[13]; p.Whh2 = (const float*)d_in[14];
    p.bih2  = (const float*)d_in[15]; p.bhh2 = (const float*)d_in[16];
    p.Wq    = (const float*)d_in[17]; p.bq   = (const float*)d_in[18];
    p.Ws1   = (const float*)d_in[19]; p.bs1  = (const float*)d_in[20];
    p.Ws2   = (const float*)d_in[21]; p.bs2  = (const float*)d_in[22];
    p.h0    = (const float*)d_in[23];
    p.c0    = (const float*)d_in[24];
    p.con   = (const float*)d_in[25];

    const int B = in_sizes[0];                  // 64
    p.T = in_sizes[1] / (B * QDIM);             // 2048
    p.S = in_sizes[3] / B;                      // 220

    // workspace layout (bytes; 16B-aligned)
    char* ws = (char*)d_ws;
    p.WH0  = (unsigned short*)(ws + 0);          // 1,048,576 B
    p.WH1  = (unsigned short*)(ws + 1048576);    // 1,310,720 B
    p.WH2  = (unsigned short*)(ws + 2359296);    // 1,310,720 B
    p.Ws1h = (unsigned short*)(ws + 3670016);    //   200,704 B
    p.bsum = (float*)(ws + 3870720);             //    12,288 B
    p.WqT4 = (float*)(ws + 3883008);             //   131,072 B
    p.Ws2T = (float*)(ws + 4014080);             //    33,792 B
    p.Ep   = (float*)(ws + 4047872);             //   135,168 B  -> end 4,183,040

    const size_t kvBytes = (size_t)B * QDIM * p.T * 2;       // 33,554,432 each
    p.keyh = (unsigned short*)(ws + 4183040);
    p.valh = (unsigned short*)(ws + 4183040 + kvBytes);
    p.dokv = (ws_size >= 4183040 + 2 * kvBytes) ? 1 : 0;

    p.outS = (float*)d_out;
    p.outP = p.outS + (size_t)B * p.S * p.T;

    prep<<<1024, 256, 0, stream>>>(p);
    if (p.dokv) speller<true ><<<B, 1024, 0, stream>>>(p);
    else        speller<false><<<B, 1024, 0, stream>>>(p);
}

// Round 16
// 14374.191 us; speedup vs baseline: 2.2641x; 1.2442x over previous
//
#include <hip/hip_runtime.h>
#include <cstddef>

#define HID   256
#define CTXD  128
#define QDIM  128
#define VDNUM 33

typedef float  float4e __attribute__((ext_vector_type(4)));
typedef unsigned int uint4e __attribute__((ext_vector_type(4)));
typedef unsigned int uint2e __attribute__((ext_vector_type(2)));

__device__ __forceinline__ float sigf(float x) { return 1.f / (1.f + expf(-x)); }

union H8 { uint4e u; _Float16 h[8]; };   // proven no-spill (rounds 7-10,14)
union H4 { uint2e u; _Float16 h[4]; };

__device__ __forceinline__ void  ast(float* pp, float v) { __hip_atomic_store(pp, v, __ATOMIC_RELAXED, __HIP_MEMORY_SCOPE_AGENT); }
__device__ __forceinline__ float ald(const float* pp)    { return __hip_atomic_load(pp, __ATOMIC_RELAXED, __HIP_MEMORY_SCOPE_AGENT); }

struct P {
    const int*   seqs;
    const float* key; const float* val; const float* embed;
    const float* Wih0; const float* Whh0; const float* bih0; const float* bhh0;
    const float* Wih1; const float* Whh1; const float* bih1; const float* bhh1;
    const float* Wih2; const float* Whh2; const float* bih2; const float* bhh2;
    const float* Wq;  const float* bq;
    const float* Ws1; const float* bs1;
    const float* Ws2; const float* bs2;
    const float* h0; const float* c0; const float* con;
    unsigned short* W0s; unsigned short* W1s; unsigned short* W2s;  // sliced fp16 LSTM weights
    unsigned short* Ws1h;
    float* bsum; float* WqT4; float* Ws2T; float* Ep;
    float* hx; float* pm; float* pz; float* cp;   // cross-block exchange (atomic access only)
    unsigned* flags;
    unsigned short* keyh; unsigned short* valh;
    int dokv;
    float* outS; float* outP;
    int S, T;
};

// ---------------------------------------------------------------------------
// One-time repack. Sliced LSTM weights: W[l][slice i][kpart kp][chunk cq][r 256][8],
// local row r = gate*64 + unit, global row = gate*256 + i*64 + unit.
// Everything else as rounds 10-14 (proven). Flags zeroed here every call.
// ---------------------------------------------------------------------------
__global__ void prep(P p)
{
    const int stride = gridDim.x * blockDim.x;
    const int i0 = blockIdx.x * blockDim.x + threadIdx.x;
    const int T = p.T;

    for (int z = i0; z < VDNUM * 1024; z += stride) {       // Ep (exact fp32)
        int c = z >> 10, r = z & 1023;
        const float* w = p.Wih0 + (size_t)r * 384;
        const float* e = p.embed + c * HID;
        float a = 0.f;
        #pragma unroll 8
        for (int k = 0; k < HID; ++k) a += e[k] * w[k];
        p.Ep[z] = a;
    }

    _Float16* w0 = (_Float16*)p.W0s;
    for (int z = i0; z < 4*4*12*256*8; z += stride) {       // L0: K=384=[ctx|h], 4x96 kparts
        int j = z & 7, r = (z >> 3) & 255;
        int cq = (z >> 11) % 12, rest = (z >> 11) / 12, kp = rest & 3, ii = rest >> 2;
        int k = kp * 96 + cq * 8 + j;
        int row = ((r >> 6) << 8) + ii * 64 + (r & 63);
        w0[z] = (_Float16)(k < 128 ? p.Wih0[(size_t)row * 384 + 256 + k]
                                   : p.Whh0[(size_t)row * 256 + (k - 128)]);
    }
    _Float16* w1 = (_Float16*)p.W1s;
    _Float16* w2 = (_Float16*)p.W2s;
    for (int z = i0; z < 4*4*16*256*8; z += stride) {       // L1/L2: K=512, 4x128 kparts
        int j = z & 7, r = (z >> 3) & 255;
        int cq = (z >> 11) & 15, rest = z >> 15, kp = rest & 3, ii = rest >> 2;
        int k = kp * 128 + cq * 8 + j;
        int row = ((r >> 6) << 8) + ii * 64 + (r & 63);
        w1[z] = (_Float16)(k < 256 ? p.Wih1[(size_t)row * 256 + k] : p.Whh1[(size_t)row * 256 + (k - 256)]);
        w2[z] = (_Float16)(k < 256 ? p.Wih2[(size_t)row * 256 + k] : p.Whh2[(size_t)row * 256 + (k - 256)]);
    }
    _Float16* ws1 = (_Float16*)p.Ws1h;
    for (int z = i0; z < 48 * 2048; z += stride) {
        int c = z >> 11, rem = z & 2047, j = rem >> 3, lane = rem & 7;
        int k = c * 8 + lane;
        ws1[z] = (_Float16)p.Ws1[(size_t)j * 384 + k];
    }
    for (int z = i0; z < 3072; z += stride) {
        int l = z >> 10, r = z & 1023;
        const float* bi = l == 0 ? p.bih0 : l == 1 ? p.bih1 : p.bih2;
        const float* bh = l == 0 ? p.bhh0 : l == 1 ? p.bhh1 : p.bhh2;
        p.bsum[z] = bi[r] + bh[r];
    }
    for (int z = i0; z < 256 * 128; z += stride) {
        int k = z >> 7, q = z & 127;
        p.WqT4[((size_t)(k >> 2) * 128 + q) * 4 + (k & 3)] = p.Wq[(size_t)q * HID + k];
    }
    for (int z = i0; z < 256 * VDNUM; z += stride) {
        int k = z / VDNUM, v = z - k * VDNUM;
        p.Ws2T[(size_t)k * VDNUM + v] = p.Ws2[(size_t)v * HID + k];
    }
    for (int z = i0; z < 4096; z += stride) p.flags[z] = 0u;
    if (p.dokv) {
        _Float16* kh = (_Float16*)p.keyh;
        _Float16* vh = (_Float16*)p.valh;
        const int NKV = 64 * QDIM * T;
        for (int z = i0; z < NKV; z += stride) kh[z] = (_Float16)p.key[z];
        for (int z = i0; z < NKV; z += stride) vh[z] = (_Float16)p.val[z];
    }
}

#define DOT8(C, xx, off) \
    a0 += (float)C.h[0] * xx[off+0] + (float)C.h[1] * xx[off+1] \
        + (float)C.h[2] * xx[off+2] + (float)C.h[3] * xx[off+3]; \
    a1 += (float)C.h[4] * xx[off+4] + (float)C.h[5] * xx[off+5] \
        + (float)C.h[6] * xx[off+6] + (float)C.h[7] * xx[off+7];

// Per-(row, kpart) sliced matvec: NCHQ chunks of 8 k, lanes r coalesced 16B.
template<int NCHQ>
__device__ __forceinline__ float matvec_slice(const unsigned short* W, int base256, const float* x)
{
    const uint4e* w = (const uint4e*)W + base256;
    float a0 = 0.f, a1 = 0.f;
    #pragma unroll
    for (int c = 0; c < NCHQ; ++c) {
        H8 cc; cc.u = w[(size_t)c * 256];
        const float* xx = x + c * 8;
        DOT8(cc, xx, 0)
    }
    return a0 + a1;
}

// ---------------------------------------------------------------------------
// Fence-free 4-block cluster sync. __syncthreads() drains each wave's vmcnt
// (compiler emits s_waitcnt vmcnt(0) before s_barrier), so all this block's
// atomic data stores are at the coherence point before the flag store. No
// acquire/release fences -> NO L2 invalidation (round-5 root cause removed).
// All cross-block data moves via relaxed AGENT atomics (coherence-point ops).
// ---------------------------------------------------------------------------
__device__ __forceinline__ void csync(unsigned* flags, int fbase, int i, unsigned& gen)
{
    __syncthreads();
    ++gen;
    if (threadIdx.x == 0)
        __hip_atomic_store(flags + ((fbase + i) << 4), gen, __ATOMIC_RELAXED, __HIP_MEMORY_SCOPE_AGENT);
    if (threadIdx.x < 4) {
        while (__hip_atomic_load(flags + ((fbase + (int)threadIdx.x) << 4),
                                 __ATOMIC_RELAXED, __HIP_MEMORY_SCOPE_AGENT) < gen)
            __builtin_amdgcn_s_sleep(1);
    }
    __syncthreads();
}

// ---------------------------------------------------------------------------
// 256 blocks x 1024 threads: cluster of 4 blocks per batch element.
// Slice i owns: 64 h-units (all 4 gates) per LSTM layer, T-quarter [i*512,..)
// of attention. Query / ctx-reduce / MLP / predict / argmax are redundant per
// block (deterministic: identical inputs via atomic exchange + same code).
// 5 cluster syncs per step. bid->(b,i) bijection places same-slice blocks on
// the same XCD (heuristic: XCD = bid%8) for weight L2 residency.
// ---------------------------------------------------------------------------
template<bool KV16>
__global__ __launch_bounds__(1024, 4) void speller(P p)
{
    __shared__ float h[3][HID];
    __shared__ float cst[3][64];
    __shared__ float ctx[CTXD];
    __shared__ float xh0[384];            // [ctx | h0_old]
    __shared__ float xh12[512];           // [h_prev | h_own_old]; reused as MLP feat [h2|ctx]
    __shared__ float gpart[4][256];
    __shared__ float gatev[256];
    __shared__ float gacc[1024];
    __shared__ float qry[QDIM];
    __shared__ float s_e[512];            // quarter energies -> scores
    __shared__ float4e ep[8][128];
    __shared__ float red[16][CTXD];
    __shared__ float cps[512];
    __shared__ float hid[HID];
    __shared__ float predp[VDNUM * 8];
    __shared__ float predv[VDNUM];
    __shared__ float wred[16];
    __shared__ float bc2[2];
    __shared__ int   chr;

    const int tid = threadIdx.x;
    const int bid = blockIdx.x;
    const int x8  = bid & 7;                       // heuristic XCD id
    const int i   = x8 >> 1;                       // slice 0..3
    const int b   = ((x8 & 1) << 5) | (bid >> 3);  // batch element 0..63 (bijective)
    const int fbase = b << 2;
    const int T = p.T, T4 = T >> 2;
    const int n = p.seqs[b];
    const int t0 = i << 9;
    unsigned gen = 0;

    if (tid < 256) {
        #pragma unroll
        for (int l = 0; l < 3; ++l) h[l][tid] = p.h0[l * 256 + tid];
    }
    if (tid < 64) {
        #pragma unroll
        for (int l = 0; l < 3; ++l) cst[l][tid] = p.c0[l * 256 + i * 64 + tid];
    }
    if (tid < 128) ctx[tid] = p.con[tid];
    if (tid == 0)  chr = 0;
    __syncthreads();

    for (int s = 0; s < p.S; ++s) {
        // ---- build L0 input [ctx | h0_old] ----
        if (tid < 128)      xh0[tid] = ctx[tid];
        else if (tid < 384) xh0[tid] = h[0][tid - 128];
        __syncthreads();

        // ---- L0: my 256 gate-rows, 4 kparts x 96 k ----
        {
            const int r = tid & 255, kp = tid >> 8;
            gpart[kp][r] = matvec_slice<12>(p.W0s, ((i * 4 + kp) * 12) * 256 + r, xh0 + kp * 96);
        }
        __syncthreads();
        if (tid < 256) {
            const int row = ((tid >> 6) << 8) + i * 64 + (tid & 63);
            gatev[tid] = ((gpart[0][tid] + gpart[1][tid]) + (gpart[2][tid] + gpart[3][tid]))
                       + p.bsum[row] + p.Ep[(size_t)chr * 1024 + row];
        }
        __syncthreads();
        if (tid < 64) {
            float gi = gatev[tid], gf = gatev[64 + tid], gg = gatev[128 + tid], go = gatev[192 + tid];
            float cn = sigf(gf) * cst[0][tid] + sigf(gi) * tanhf(gg);
            cst[0][tid] = cn;
            ast(p.hx + 0 * 16384 + b * 256 + i * 64 + tid, sigf(go) * tanhf(cn));
        }
        csync(p.flags, fbase, i, gen);                        // S1
        if (tid < 256) {
            float v = ald(p.hx + 0 * 16384 + b * 256 + tid);
            h[0][tid] = v; xh12[tid] = v; xh12[256 + tid] = h[1][tid];
        }
        __syncthreads();

        // ---- L1 ----
        {
            const int r = tid & 255, kp = tid >> 8;
            gpart[kp][r] = matvec_slice<16>(p.W1s, ((i * 4 + kp) * 16) * 256 + r, xh12 + kp * 128);
        }
        __syncthreads();
        if (tid < 256) {
            const int row = ((tid >> 6) << 8) + i * 64 + (tid & 63);
            gatev[tid] = ((gpart[0][tid] + gpart[1][tid]) + (gpart[2][tid] + gpart[3][tid]))
                       + p.bsum[1024 + row];
        }
        __syncthreads();
        if (tid < 64) {
            float gi = gatev[tid], gf = gatev[64 + tid], gg = gatev[128 + tid], go = gatev[192 + tid];
            float cn = sigf(gf) * cst[1][tid] + sigf(gi) * tanhf(gg);
            cst[1][tid] = cn;
            ast(p.hx + 1 * 16384 + b * 256 + i * 64 + tid, sigf(go) * tanhf(cn));
        }
        csync(p.flags, fbase, i, gen);                        // S2
        if (tid < 256) {
            float v = ald(p.hx + 1 * 16384 + b * 256 + tid);
            h[1][tid] = v; xh12[tid] = v; xh12[256 + tid] = h[2][tid];
        }
        __syncthreads();

        // ---- L2 ----
        {
            const int r = tid & 255, kp = tid >> 8;
            gpart[kp][r] = matvec_slice<16>(p.W2s, ((i * 4 + kp) * 16) * 256 + r, xh12 + kp * 128);
        }
        __syncthreads();
        if (tid < 256) {
            const int row = ((tid >> 6) << 8) + i * 64 + (tid & 63);
            gatev[tid] = ((gpart[0][tid] + gpart[1][tid]) + (gpart[2][tid] + gpart[3][tid]))
                       + p.bsum[2048 + row];
        }
        __syncthreads();
        if (tid < 64) {
            float gi = gatev[tid], gf = gatev[64 + tid], gg = gatev[128 + tid], go = gatev[192 + tid];
            float cn = sigf(gf) * cst[2][tid] + sigf(gi) * tanhf(gg);
            cst[2][tid] = cn;
            ast(p.hx + 2 * 16384 + b * 256 + i * 64 + tid, sigf(go) * tanhf(cn));
        }
        csync(p.flags, fbase, i, gen);                        // S3
        if (tid < 256) h[2][tid] = ald(p.hx + 2 * 16384 + b * 256 + tid);
        __syncthreads();

        // ---- query (redundant per block) ----
        {
            const int q = tid & 127, ch = tid >> 7;
            const float4e* w = (const float4e*)p.WqT4 + q;
            float a = 0;
            #pragma unroll
            for (int u = 0; u < 8; ++u) {
                int k4 = ch * 8 + u;
                float4e wv = w[(size_t)k4 * 128];
                const float* x = &h[2][k4 * 4];
                a += x[0] * wv.x + x[1] * wv.y + x[2] * wv.z + x[3] * wv.w;
            }
            gacc[ch * 128 + q] = a;
        }
        __syncthreads();
        if (tid < QDIM) {
            float a = p.bq[tid];
            #pragma unroll
            for (int u = 0; u < 8; ++u) a += gacc[u * 128 + tid];
            qry[tid] = a;
        }
        __syncthreads();

        // ---- Phase D: energy on my T-quarter + partial (max, expsum) ----
        {
            const int tl = tid & 127, kq = tid >> 7;      // 128 t4-slots x 8 q-groups of 16
            float4e e = {0.f, 0.f, 0.f, 0.f};
            if (t0 < n) {
                const int q0 = kq * 16;
                if (KV16) {
                    const uint2e* k2 = (const uint2e*)p.keyh + (((size_t)b * QDIM * T + t0) >> 2) + tl;
                    #pragma unroll
                    for (int qq = 0; qq < 16; ++qq) {
                        H4 kv; kv.u = k2[(size_t)(q0 + qq) * (T >> 2)];
                        float qv = qry[q0 + qq];
                        e.x += qv * (float)kv.h[0];
                        e.y += qv * (float)kv.h[1];
                        e.z += qv * (float)kv.h[2];
                        e.w += qv * (float)kv.h[3];
                    }
                } else {
                    const float4e* k4 = (const float4e*)p.key + (size_t)b * QDIM * T4 + (t0 >> 2) + tl;
                    #pragma unroll
                    for (int qq = 0; qq < 16; ++qq) {
                        float4e kv = k4[(size_t)(q0 + qq) * T4];
                        e += qry[q0 + qq] * kv;
                    }
                }
            }
            ep[kq][tl] = e;
        }
        __syncthreads();
        if (tid < 128) {
            float4e r4 = ((ep[0][tid] + ep[1][tid]) + (ep[2][tid] + ep[3][tid]))
                       + ((ep[4][tid] + ep[5][tid]) + (ep[6][tid] + ep[7][tid]));
            ((float4e*)s_e)[tid] = r4;
        }
        __syncthreads();
        {
            float mq = -INFINITY;
            if (tid < 512 && (t0 + tid) < n) mq = s_e[tid];
            #pragma unroll
            for (int off = 32; off; off >>= 1) mq = fmaxf(mq, __shfl_xor(mq, off));
            if ((tid & 63) == 0) wred[tid >> 6] = mq;
            __syncthreads();
            if (tid == 0) {
                float r = wred[0];
                #pragma unroll
                for (int u = 1; u < 16; ++u) r = fmaxf(r, wred[u]);
                bc2[0] = r;
            }
            __syncthreads();
            const float mqv = bc2[0];
            float zq = (tid < 512 && (t0 + tid) < n) ? expf(s_e[tid] - mqv) : 0.f;
            #pragma unroll
            for (int off = 32; off; off >>= 1) zq += __shfl_xor(zq, off);
            if ((tid & 63) == 0) wred[tid >> 6] = zq;
            __syncthreads();
            if (tid == 0) {
                float r = 0.f;
                #pragma unroll
                for (int u = 0; u < 16; ++u) r += wred[u];
                ast(p.pm + b * 4 + i, mqv);
                ast(p.pz + b * 4 + i, r);
            }
        }
        csync(p.flags, fbase, i, gen);                        // S4

        // ---- Phase E: merge stats, scores + ctx partial for my quarter ----
        if (tid < 4)      wred[tid] = ald(p.pm + b * 4 + tid);
        else if (tid < 8) wred[tid] = ald(p.pz + b * 4 + tid - 4);
        __syncthreads();
        if (tid == 0) {
            float m = fmaxf(fmaxf(wred[0], wred[1]), fmaxf(wred[2], wred[3]));
            float Z = wred[4] * expf(wred[0] - m) + wred[5] * expf(wred[1] - m)
                    + wred[6] * expf(wred[2] - m) + wred[7] * expf(wred[3] - m);
            bc2[0] = m; bc2[1] = Z;
        }
        __syncthreads();
        {
            const float m = bc2[0], Z = bc2[1];
            float* so = p.outS + ((size_t)b * p.S + s) * T + t0;
            if (tid < 512) {
                const int t = t0 + tid;
                float sc = (t < n) ? expf(s_e[tid] - m) / Z : 0.f;
                s_e[tid] = sc;
                __builtin_nontemporal_store(sc, so + tid);
            }
        }
        __syncthreads();
        {
            const int tg = tid >> 5, cq = tid & 31;
            float ax = 0, ay = 0, az = 0, aw = 0;
            const int tend = min(t0 + 512, n);
            if (KV16) {
                const uint2e* v2 = (const uint2e*)p.valh + (size_t)b * T * 32 + cq;
                for (int t = t0 + tg; t < tend; t += 32) {
                    float sv = s_e[t - t0];
                    H4 vv; vv.u = v2[(size_t)t * 32];
                    ax += sv * (float)vv.h[0]; ay += sv * (float)vv.h[1];
                    az += sv * (float)vv.h[2]; aw += sv * (float)vv.h[3];
                }
            } else {
                const float4e* v4 = (const float4e*)p.val + (size_t)b * T * 32 + cq;
                for (int t = t0 + tg; t < tend; t += 32) {
                    float   sv = s_e[t - t0];
                    float4e vv = v4[(size_t)t * 32];
                    ax += sv * vv.x; ay += sv * vv.y; az += sv * vv.z; aw += sv * vv.w;
                }
            }
            ax += __shfl_xor(ax, 32); ay += __shfl_xor(ay, 32);
            az += __shfl_xor(az, 32); aw += __shfl_xor(aw, 32);
            if ((tid & 63) < 32) {
                const int w = tid >> 6;
                red[w][cq * 4 + 0] = ax; red[w][cq * 4 + 1] = ay;
                red[w][cq * 4 + 2] = az; red[w][cq * 4 + 3] = aw;
            }
        }
        __syncthreads();
        if (tid < 128) {
            float a = 0.f;
            #pragma unroll
            for (int w = 0; w < 16; ++w) a += red[w][tid];
            ast(p.cp + ((size_t)b * 4 + i) * 128 + tid, a);
        }
        csync(p.flags, fbase, i, gen);                        // S5

        // ---- Phase F (redundant per block): ctx reduce, MLP, predict, argmax ----
        if (tid < 512) cps[tid] = ald(p.cp + ((size_t)b * 4 + (tid >> 7)) * 128 + (tid & 127));
        __syncthreads();
        if (tid < 128) {
            float a = ((cps[tid] + cps[128 + tid]) + (cps[256 + tid] + cps[384 + tid]));
            ctx[tid] = a;
            xh12[256 + tid] = a;           // feat[256..383] = ctx_new
        }
        if (tid < 256) xh12[tid] = h[2][tid];   // feat[0..255] = h2
        __syncthreads();
        {
            const int j = tid & 255, ch = tid >> 8;
            const uint4e* w = (const uint4e*)p.Ws1h + (size_t)(ch * 12) * 256 + j;
            H8 cc; cc.u = w[0];
            float a = 0.f;
            #pragma unroll 2
            for (int u = 0; u < 12; ++u) {
                H8 nx; nx.u = w[(size_t)(u + 1) * 256];
                const float* x = xh12 + (ch * 12 + u) * 8;
                a += (float)cc.h[0] * x[0] + (float)cc.h[1] * x[1]
                   + (float)cc.h[2] * x[2] + (float)cc.h[3] * x[3]
                   + (float)cc.h[4] * x[4] + (float)cc.h[5] * x[5]
                   + (float)cc.h[6] * x[6] + (float)cc.h[7] * x[7];
                cc = nx;
            }
            gacc[ch * 256 + j] = a;
        }
        __syncthreads();
        if (tid < HID)
            hid[tid] = fmaxf(p.bs1[tid] + ((gacc[tid] + gacc[256 + tid]) + (gacc[512 + tid] + gacc[768 + tid])), 0.f);
        __syncthreads();
        if (tid < VDNUM * 8) {
            const int v = tid >> 3, oct = tid & 7;
            const float* w2 = p.Ws2T + (size_t)oct * 32 * VDNUM + v;
            float a = 0.f;
            #pragma unroll 8
            for (int k = 0; k < 32; ++k) a += hid[oct * 32 + k] * w2[(size_t)k * VDNUM];
            predp[v * 8 + oct] = a;
        }
        __syncthreads();
        if (tid < VDNUM) {
            float a = p.bs2[tid];
            #pragma unroll
            for (int o = 0; o < 8; ++o) a += predp[tid * 8 + o];
            predv[tid] = a;
            if (i == 0) __builtin_nontemporal_store(a, p.outP + ((size_t)b * p.S + s) * VDNUM + tid);
        }
        __syncthreads();
        if (tid == 0) {   // first-occurrence argmax (strict >) — identical in all 4 blocks
            int best = 0; float bv = predv[0];
            for (int v = 1; v < VDNUM; ++v) if (predv[v] > bv) { bv = predv[v]; best = v; }
            chr = best;
        }
        __syncthreads();
    }
}

extern "C" void kernel_launch(void* const* d_in, const int* in_sizes, int n_in,
                              void* d_out, int out_size, void* d_ws, size_t ws_size,
                              hipStream_t stream)
{
    P p;
    p.seqs  = (const int*)  d_in[0];
    p.key   = (const float*)d_in[1];
    p.val   = (const float*)d_in[2];
    p.embed = (const float*)d_in[4];
    p.Wih0  = (const float*)d_in[5];  p.Whh0 = (const float*)d_in[6];
    p.bih0  = (const float*)d_in[7];  p.bhh0 = (const float*)d_in[8];
    p.Wih1  = (const float*)d_in[9];  p.Whh1 = (const float*)d_in[10];
    p.bih1  = (const float*)d_in[11]; p.bhh1 = (const float*)d_in[12];
    p.Wih2  = (const float*)d_in[13]; p.Whh2 = (const float*)d_in[14];
    p.bih2  = (const float*)d_in[15]; p.bhh2 = (const float*)d_in[16];
    p.Wq    = (const float*)d_in[17]; p.bq   = (const float*)d_in[18];
    p.Ws1   = (const float*)d_in[19]; p.bs1  = (const float*)d_in[20];
    p.Ws2   = (const float*)d_in[21]; p.bs2  = (const float*)d_in[22];
    p.h0    = (const float*)d_in[23];
    p.c0    = (const float*)d_in[24];
    p.con   = (const float*)d_in[25];

    const int B = in_sizes[0];                  // 64
    p.T = in_sizes[1] / (B * QDIM);             // 2048
    p.S = in_sizes[3] / B;                      // 220

    // workspace layout (bytes; 16B-aligned)
    char* ws = (char*)d_ws;
    p.W0s   = (unsigned short*)(ws + 0);         //   786,432 B
    p.W1s   = (unsigned short*)(ws + 786432);    // 1,048,576 B
    p.W2s   = (unsigned short*)(ws + 1835008);   // 1,048,576 B
    p.Ws1h  = (unsigned short*)(ws + 2883584);   //   200,704 B
    p.bsum  = (float*)(ws + 3084288);            //    12,288 B
    p.WqT4  = (float*)(ws + 3096576);            //   131,072 B
    p.Ws2T  = (float*)(ws + 3227648);            //    33,792 B
    p.Ep    = (float*)(ws + 3261440);            //   135,168 B
    p.flags = (unsigned*)(ws + 3396608);         //    16,384 B
    p.hx    = (float*)(ws + 3412992);            //   196,608 B (3 x 64 x 256)
    p.pm    = (float*)(ws + 3609600);            //     1,024 B
    p.pz    = (float*)(ws + 3610624);            //     1,024 B
    p.cp    = (float*)(ws + 3611648);            //   131,072 B
    const size_t kvBytes = (size_t)B * QDIM * p.T * 2;   // 33,554,432 each
    p.keyh  = (unsigned short*)(ws + 3742720);
    p.valh  = (unsigned short*)(ws + 3742720 + kvBytes);
    p.dokv  = (ws_size >= 3742720 + 2 * kvBytes) ? 1 : 0;

    p.outS = (float*)d_out;
    p.outP = p.outS + (size_t)B * p.S * p.T;

    prep<<<1024, 256, 0, stream>>>(p);
    if (p.dokv) speller<true ><<<256, 1024, 0, stream>>>(p);
    else        speller<false><<<256, 1024, 0, stream>>>(p);
}

// Round 17
// 14237.564 us; speedup vs baseline: 2.2858x; 1.0096x over previous
//
#include <hip/hip_runtime.h>
#include <cstddef>

#define HID   256
#define CTXD  128
#define QDIM  128
#define VDNUM 33

typedef float  float4e __attribute__((ext_vector_type(4)));
typedef unsigned int uint4e __attribute__((ext_vector_type(4)));
typedef unsigned int uint2e __attribute__((ext_vector_type(2)));

__device__ __forceinline__ float sigf(float x) { return 1.f / (1.f + expf(-x)); }

union H8 { uint4e u; _Float16 h[8]; };   // proven no-spill (rounds 7-10,14,15)
union H4 { uint2e u; _Float16 h[4]; };

__device__ __forceinline__ void  ast(float* pp, float v) { __hip_atomic_store(pp, v, __ATOMIC_RELAXED, __HIP_MEMORY_SCOPE_AGENT); }
__device__ __forceinline__ float ald(const float* pp)    { return __hip_atomic_load(pp, __ATOMIC_RELAXED, __HIP_MEMORY_SCOPE_AGENT); }

struct P {
    const int*   seqs;
    const float* key; const float* val; const float* embed;
    const float* Wih0; const float* Whh0; const float* bih0; const float* bhh0;
    const float* Wih1; const float* Whh1; const float* bih1; const float* bhh1;
    const float* Wih2; const float* Whh2; const float* bih2; const float* bhh2;
    const float* Wq;  const float* bq;
    const float* Ws1; const float* bs1;
    const float* Ws2; const float* bs2;
    const float* h0; const float* c0; const float* con;
    unsigned short* W0s; unsigned short* W1s; unsigned short* W2s;  // sliced fp16 LSTM weights
    unsigned short* Ws1h;
    float* bsum; float* WqT4; float* Ws2T; float* Ep;
    float* hx; float* pm; float* pz; float* cp;   // cross-block exchange (atomic access only)
    unsigned* flags;
    unsigned short* keyh; unsigned short* valh;
    int dokv;
    float* outS; float* outP;
    int S, T;
};

// ---------------------------------------------------------------------------
// One-time repack (identical to round 15, which passed).
// ---------------------------------------------------------------------------
__global__ void prep(P p)
{
    const int stride = gridDim.x * blockDim.x;
    const int i0 = blockIdx.x * blockDim.x + threadIdx.x;
    const int T = p.T;

    for (int z = i0; z < VDNUM * 1024; z += stride) {       // Ep (exact fp32)
        int c = z >> 10, r = z & 1023;
        const float* w = p.Wih0 + (size_t)r * 384;
        const float* e = p.embed + c * HID;
        float a = 0.f;
        #pragma unroll 8
        for (int k = 0; k < HID; ++k) a += e[k] * w[k];
        p.Ep[z] = a;
    }

    _Float16* w0 = (_Float16*)p.W0s;
    for (int z = i0; z < 4*4*12*256*8; z += stride) {       // L0: K=384=[ctx|h]
        int j = z & 7, r = (z >> 3) & 255;
        int cq = (z >> 11) % 12, rest = (z >> 11) / 12, kp = rest & 3, ii = rest >> 2;
        int k = kp * 96 + cq * 8 + j;
        int row = ((r >> 6) << 8) + ii * 64 + (r & 63);
        w0[z] = (_Float16)(k < 128 ? p.Wih0[(size_t)row * 384 + 256 + k]
                                   : p.Whh0[(size_t)row * 256 + (k - 128)]);
    }
    _Float16* w1 = (_Float16*)p.W1s;
    _Float16* w2 = (_Float16*)p.W2s;
    for (int z = i0; z < 4*4*16*256*8; z += stride) {       // L1/L2: K=512
        int j = z & 7, r = (z >> 3) & 255;
        int cq = (z >> 11) & 15, rest = z >> 15, kp = rest & 3, ii = rest >> 2;
        int k = kp * 128 + cq * 8 + j;
        int row = ((r >> 6) << 8) + ii * 64 + (r & 63);
        w1[z] = (_Float16)(k < 256 ? p.Wih1[(size_t)row * 256 + k] : p.Whh1[(size_t)row * 256 + (k - 256)]);
        w2[z] = (_Float16)(k < 256 ? p.Wih2[(size_t)row * 256 + k] : p.Whh2[(size_t)row * 256 + (k - 256)]);
    }
    _Float16* ws1 = (_Float16*)p.Ws1h;
    for (int z = i0; z < 48 * 2048; z += stride) {
        int c = z >> 11, rem = z & 2047, j = rem >> 3, lane = rem & 7;
        int k = c * 8 + lane;
        ws1[z] = (_Float16)p.Ws1[(size_t)j * 384 + k];
    }
    for (int z = i0; z < 3072; z += stride) {
        int l = z >> 10, r = z & 1023;
        const float* bi = l == 0 ? p.bih0 : l == 1 ? p.bih1 : p.bih2;
        const float* bh = l == 0 ? p.bhh0 : l == 1 ? p.bhh1 : p.bhh2;
        p.bsum[z] = bi[r] + bh[r];
    }
    for (int z = i0; z < 256 * 128; z += stride) {
        int k = z >> 7, q = z & 127;
        p.WqT4[((size_t)(k >> 2) * 128 + q) * 4 + (k & 3)] = p.Wq[(size_t)q * HID + k];
    }
    for (int z = i0; z < 256 * VDNUM; z += stride) {
        int k = z / VDNUM, v = z - k * VDNUM;
        p.Ws2T[(size_t)k * VDNUM + v] = p.Ws2[(size_t)v * HID + k];
    }
    for (int z = i0; z < 4096; z += stride) p.flags[z] = 0u;
    if (p.dokv) {
        _Float16* kh = (_Float16*)p.keyh;
        _Float16* vh = (_Float16*)p.valh;
        const int NKV = 64 * QDIM * T;
        for (int z = i0; z < NKV; z += stride) kh[z] = (_Float16)p.key[z];
        for (int z = i0; z < NKV; z += stride) vh[z] = (_Float16)p.val[z];
    }
}

#define DOT8(C, xx, off) \
    a0 += (float)C.h[0] * xx[off+0] + (float)C.h[1] * xx[off+1] \
        + (float)C.h[2] * xx[off+2] + (float)C.h[3] * xx[off+3]; \
    a1 += (float)C.h[4] * xx[off+4] + (float)C.h[5] * xx[off+5] \
        + (float)C.h[6] * xx[off+6] + (float)C.h[7] * xx[off+7];

template<int NCHQ>
__device__ __forceinline__ float matvec_slice(const unsigned short* W, int base256, const float* x)
{
    const uint4e* w = (const uint4e*)W + base256;
    float a0 = 0.f, a1 = 0.f;
    #pragma unroll
    for (int c = 0; c < NCHQ; ++c) {
        H8 cc; cc.u = w[(size_t)c * 256];
        const float* xx = x + c * 8;
        DOT8(cc, xx, 0)
    }
    return a0 + a1;
}

// ---------------------------------------------------------------------------
// Fence-free 4-block cluster sync (proven round 15): __syncthreads drains
// vmcnt before s_barrier, so the block's relaxed-atomic data stores are at
// the coherence point before the flag store. No acquire fences -> no L2
// invalidation. Cross-block data moves via relaxed AGENT atomics only.
// ---------------------------------------------------------------------------
__device__ __forceinline__ void csync(unsigned* flags, int fbase, int i, unsigned& gen)
{
    __syncthreads();
    ++gen;
    if (threadIdx.x == 0)
        __hip_atomic_store(flags + ((fbase + i) << 4), gen, __ATOMIC_RELAXED, __HIP_MEMORY_SCOPE_AGENT);
    if (threadIdx.x < 4) {
        while (__hip_atomic_load(flags + ((fbase + (int)threadIdx.x) << 4),
                                 __ATOMIC_RELAXED, __HIP_MEMORY_SCOPE_AGENT) < gen)
            __builtin_amdgcn_s_sleep(1);
    }
    __syncthreads();
}

// ---------------------------------------------------------------------------
// 256 blocks x 1024 threads, 4 blocks per batch element. NOW 4 syncs/step:
// S1-S3 (h exchange) + S4 (merged attention partials). Attention uses
// LOCAL-max unnormalized partials: p_t = exp(e_t - m_i), ctxp_i = sum p_t*v;
// exchange (m_i, z_i, ctxp_i) once; merge gives global m,Z; scores and ctx
// are rescaled by exp(m_i - m)/Z (ulp-class perturbation).
// ---------------------------------------------------------------------------
template<bool KV16>
__global__ __launch_bounds__(1024, 4) void speller(P p)
{
    __shared__ float h[3][HID];
    __shared__ float cst[3][64];
    __shared__ float ctx[CTXD];
    __shared__ float xh0[384];
    __shared__ float xh12[512];
    __shared__ float gpart[4][256];
    __shared__ float gatev[256];
    __shared__ float gacc[1024];
    __shared__ float qry[QDIM];
    __shared__ float s_e[512];            // quarter energies -> p_t
    __shared__ float4e ep[8][128];
    __shared__ float red[16][CTXD];
    __shared__ float cps[512];
    __shared__ float hid[HID];
    __shared__ float predp[VDNUM * 8];
    __shared__ float predv[VDNUM];
    __shared__ float wred[16];
    __shared__ float bc2[2];
    __shared__ int   chr;

    const int tid = threadIdx.x;
    const int bid = blockIdx.x;
    const int x8  = bid & 7;
    const int i   = x8 >> 1;
    const int b   = ((x8 & 1) << 5) | (bid >> 3);
    const int fbase = b << 2;
    const int T = p.T, T4 = T >> 2;
    const int n = p.seqs[b];
    const int t0 = i << 9;
    unsigned gen = 0;

    if (tid < 256) {
        #pragma unroll
        for (int l = 0; l < 3; ++l) h[l][tid] = p.h0[l * 256 + tid];
    }
    if (tid < 64) {
        #pragma unroll
        for (int l = 0; l < 3; ++l) cst[l][tid] = p.c0[l * 256 + i * 64 + tid];
    }
    if (tid < 128) ctx[tid] = p.con[tid];
    if (tid == 0)  chr = 0;
    __syncthreads();

    for (int s = 0; s < p.S; ++s) {
        // ---- build L0 input [ctx | h0_old] ----
        if (tid < 128)      xh0[tid] = ctx[tid];
        else if (tid < 384) xh0[tid] = h[0][tid - 128];
        __syncthreads();

        // ---- L0 ----
        {
            const int r = tid & 255, kp = tid >> 8;
            gpart[kp][r] = matvec_slice<12>(p.W0s, ((i * 4 + kp) * 12) * 256 + r, xh0 + kp * 96);
        }
        __syncthreads();
        if (tid < 256) {
            const int row = ((tid >> 6) << 8) + i * 64 + (tid & 63);
            gatev[tid] = ((gpart[0][tid] + gpart[1][tid]) + (gpart[2][tid] + gpart[3][tid]))
                       + p.bsum[row] + p.Ep[(size_t)chr * 1024 + row];
        }
        __syncthreads();
        if (tid < 64) {
            float gi = gatev[tid], gf = gatev[64 + tid], gg = gatev[128 + tid], go = gatev[192 + tid];
            float cn = sigf(gf) * cst[0][tid] + sigf(gi) * tanhf(gg);
            cst[0][tid] = cn;
            ast(p.hx + 0 * 16384 + b * 256 + i * 64 + tid, sigf(go) * tanhf(cn));
        }
        csync(p.flags, fbase, i, gen);                        // S1
        if (tid < 256) {
            float v = ald(p.hx + 0 * 16384 + b * 256 + tid);
            h[0][tid] = v; xh12[tid] = v; xh12[256 + tid] = h[1][tid];
        }
        __syncthreads();

        // ---- L1 ----
        {
            const int r = tid & 255, kp = tid >> 8;
            gpart[kp][r] = matvec_slice<16>(p.W1s, ((i * 4 + kp) * 16) * 256 + r, xh12 + kp * 128);
        }
        __syncthreads();
        if (tid < 256) {
            const int row = ((tid >> 6) << 8) + i * 64 + (tid & 63);
            gatev[tid] = ((gpart[0][tid] + gpart[1][tid]) + (gpart[2][tid] + gpart[3][tid]))
                       + p.bsum[1024 + row];
        }
        __syncthreads();
        if (tid < 64) {
            float gi = gatev[tid], gf = gatev[64 + tid], gg = gatev[128 + tid], go = gatev[192 + tid];
            float cn = sigf(gf) * cst[1][tid] + sigf(gi) * tanhf(gg);
            cst[1][tid] = cn;
            ast(p.hx + 1 * 16384 + b * 256 + i * 64 + tid, sigf(go) * tanhf(cn));
        }
        csync(p.flags, fbase, i, gen);                        // S2
        if (tid < 256) {
            float v = ald(p.hx + 1 * 16384 + b * 256 + tid);
            h[1][tid] = v; xh12[tid] = v; xh12[256 + tid] = h[2][tid];
        }
        __syncthreads();

        // ---- L2 ----
        {
            const int r = tid & 255, kp = tid >> 8;
            gpart[kp][r] = matvec_slice<16>(p.W2s, ((i * 4 + kp) * 16) * 256 + r, xh12 + kp * 128);
        }
        __syncthreads();
        if (tid < 256) {
            const int row = ((tid >> 6) << 8) + i * 64 + (tid & 63);
            gatev[tid] = ((gpart[0][tid] + gpart[1][tid]) + (gpart[2][tid] + gpart[3][tid]))
                       + p.bsum[2048 + row];
        }
        __syncthreads();
        if (tid < 64) {
            float gi = gatev[tid], gf = gatev[64 + tid], gg = gatev[128 + tid], go = gatev[192 + tid];
            float cn = sigf(gf) * cst[2][tid] + sigf(gi) * tanhf(gg);
            cst[2][tid] = cn;
            ast(p.hx + 2 * 16384 + b * 256 + i * 64 + tid, sigf(go) * tanhf(cn));
        }
        csync(p.flags, fbase, i, gen);                        // S3
        if (tid < 256) h[2][tid] = ald(p.hx + 2 * 16384 + b * 256 + tid);
        __syncthreads();

        // ---- query (redundant per block) ----
        {
            const int q = tid & 127, ch = tid >> 7;
            const float4e* w = (const float4e*)p.WqT4 + q;
            float a = 0;
            #pragma unroll
            for (int u = 0; u < 8; ++u) {
                int k4 = ch * 8 + u;
                float4e wv = w[(size_t)k4 * 128];
                const float* x = &h[2][k4 * 4];
                a += x[0] * wv.x + x[1] * wv.y + x[2] * wv.z + x[3] * wv.w;
            }
            gacc[ch * 128 + q] = a;
        }
        __syncthreads();
        if (tid < QDIM) {
            float a = p.bq[tid];
            #pragma unroll
            for (int u = 0; u < 8; ++u) a += gacc[u * 128 + tid];
            qry[tid] = a;
        }
        __syncthreads();

        // ---- Phase D: energy, LOCAL softmax partials, unnormalized ctx partial ----
        {
            const int tl = tid & 127, kq = tid >> 7;
            float4e e = {0.f, 0.f, 0.f, 0.f};
            if (t0 < n) {
                const int q0 = kq * 16;
                if (KV16) {
                    const uint2e* k2 = (const uint2e*)p.keyh + (((size_t)b * QDIM * T + t0) >> 2) + tl;
                    #pragma unroll
                    for (int qq = 0; qq < 16; ++qq) {
                        H4 kv; kv.u = k2[(size_t)(q0 + qq) * (T >> 2)];
                        float qv = qry[q0 + qq];
                        e.x += qv * (float)kv.h[0];
                        e.y += qv * (float)kv.h[1];
                        e.z += qv * (float)kv.h[2];
                        e.w += qv * (float)kv.h[3];
                    }
                } else {
                    const float4e* k4 = (const float4e*)p.key + (size_t)b * QDIM * T4 + (t0 >> 2) + tl;
                    #pragma unroll
                    for (int qq = 0; qq < 16; ++qq) {
                        float4e kv = k4[(size_t)(q0 + qq) * T4];
                        e += qry[q0 + qq] * kv;
                    }
                }
            }
            ep[kq][tl] = e;
        }
        __syncthreads();
        if (tid < 128) {
            float4e r4 = ((ep[0][tid] + ep[1][tid]) + (ep[2][tid] + ep[3][tid]))
                       + ((ep[4][tid] + ep[5][tid]) + (ep[6][tid] + ep[7][tid]));
            ((float4e*)s_e)[tid] = r4;
        }
        __syncthreads();
        {
            // local max m_i over my quarter
            float mq = -INFINITY;
            if (tid < 512 && (t0 + tid) < n) mq = s_e[tid];
            #pragma unroll
            for (int off = 32; off; off >>= 1) mq = fmaxf(mq, __shfl_xor(mq, off));
            if ((tid & 63) == 0) wred[tid >> 6] = mq;
            __syncthreads();
            if (tid == 0) {
                float r = wred[0];
                #pragma unroll
                for (int u = 1; u < 16; ++u) r = fmaxf(r, wred[u]);
                bc2[0] = r;
            }
            __syncthreads();
            const float mi = bc2[0];
            // p_t = exp(e - m_i) in s_e; local z_i
            float zq = 0.f;
            if (tid < 512) {
                float pv = 0.f;
                if ((t0 + tid) < n) pv = expf(s_e[tid] - mi);
                s_e[tid] = pv;
                zq = pv;
            }
            #pragma unroll
            for (int off = 32; off; off >>= 1) zq += __shfl_xor(zq, off);
            if ((tid & 63) == 0) wred[tid >> 6] = zq;
            __syncthreads();
            if (tid == 0) {
                float r = 0.f;
                #pragma unroll
                for (int u = 0; u < 16; ++u) r += wred[u];
                ast(p.pm + b * 4 + i, mi);
                ast(p.pz + b * 4 + i, r);
            }
        }
        __syncthreads();
        {   // unnormalized ctx partial with p_t
            const int tg = tid >> 5, cq = tid & 31;
            float ax = 0, ay = 0, az = 0, aw = 0;
            const int tend = min(t0 + 512, n);
            if (KV16) {
                const uint2e* v2 = (const uint2e*)p.valh + (size_t)b * T * 32 + cq;
                for (int t = t0 + tg; t < tend; t += 32) {
                    float sv = s_e[t - t0];
                    H4 vv; vv.u = v2[(size_t)t * 32];
                    ax += sv * (float)vv.h[0]; ay += sv * (float)vv.h[1];
                    az += sv * (float)vv.h[2]; aw += sv * (float)vv.h[3];
                }
            } else {
                const float4e* v4 = (const float4e*)p.val + (size_t)b * T * 32 + cq;
                for (int t = t0 + tg; t < tend; t += 32) {
                    float   sv = s_e[t - t0];
                    float4e vv = v4[(size_t)t * 32];
                    ax += sv * vv.x; ay += sv * vv.y; az += sv * vv.z; aw += sv * vv.w;
                }
            }
            ax += __shfl_xor(ax, 32); ay += __shfl_xor(ay, 32);
            az += __shfl_xor(az, 32); aw += __shfl_xor(aw, 32);
            if ((tid & 63) < 32) {
                const int w = tid >> 6;
                red[w][cq * 4 + 0] = ax; red[w][cq * 4 + 1] = ay;
                red[w][cq * 4 + 2] = az; red[w][cq * 4 + 3] = aw;
            }
        }
        __syncthreads();
        if (tid < 128) {
            float a = 0.f;
            #pragma unroll
            for (int w = 0; w < 16; ++w) a += red[w][tid];
            ast(p.cp + ((size_t)b * 4 + i) * 128 + tid, a);
        }
        csync(p.flags, fbase, i, gen);                        // S4 (merged)

        // ---- Phase F: merge stats, scores, ctx reduce, MLP, predict, argmax ----
        if (tid < 4)      wred[tid] = ald(p.pm + b * 4 + tid);
        else if (tid < 8) wred[tid] = ald(p.pz + b * 4 + tid - 4);
        if (tid < 512)    cps[tid] = ald(p.cp + ((size_t)b * 4 + (tid >> 7)) * 128 + (tid & 127));
        __syncthreads();
        if (tid == 0) {
            float m = fmaxf(fmaxf(wred[0], wred[1]), fmaxf(wred[2], wred[3]));
            float Z = wred[4] * expf(wred[0] - m) + wred[5] * expf(wred[1] - m)
                    + wred[6] * expf(wred[2] - m) + wred[7] * expf(wred[3] - m);
            bc2[0] = m; bc2[1] = Z;
        }
        __syncthreads();
        {
            const float m = bc2[0], Z = bc2[1];
            const float scl = (t0 < n) ? expf(wred[i] - m) / Z : 0.f;   // own-quarter rescale
            float* so = p.outS + ((size_t)b * p.S + s) * T + t0;
            if (tid < 512)
                __builtin_nontemporal_store(s_e[tid] * scl, so + tid);
        }
        if (tid < 128) {
            const float m = bc2[0], Z = bc2[1];
            float a = 0.f;
            #pragma unroll
            for (int j2 = 0; j2 < 4; ++j2)
                a += cps[j2 * 128 + tid] * (expf(wred[j2] - m) / Z);    // -inf -> 0, cps 0
            ctx[tid] = a;
            xh12[256 + tid] = a;           // feat[256..383] = ctx_new
        }
        if (tid < 256) xh12[tid] = h[2][tid];   // feat[0..255] = h2
        __syncthreads();
        {
            const int j = tid & 255, ch = tid >> 8;
            const uint4e* w = (const uint4e*)p.Ws1h + (size_t)(ch * 12) * 256 + j;
            H8 cc; cc.u = w[0];
            float a = 0.f;
            #pragma unroll 2
            for (int u = 0; u < 12; ++u) {
                H8 nx; nx.u = w[(size_t)(u + 1) * 256];
                const float* x = xh12 + (ch * 12 + u) * 8;
                a += (float)cc.h[0] * x[0] + (float)cc.h[1] * x[1]
                   + (float)cc.h[2] * x[2] + (float)cc.h[3] * x[3]
                   + (float)cc.h[4] * x[4] + (float)cc.h[5] * x[5]
                   + (float)cc.h[6] * x[6] + (float)cc.h[7] * x[7];
                cc = nx;
            }
            gacc[ch * 256 + j] = a;
        }
        __syncthreads();
        if (tid < HID)
            hid[tid] = fmaxf(p.bs1[tid] + ((gacc[tid] + gacc[256 + tid]) + (gacc[512 + tid] + gacc[768 + tid])), 0.f);
        __syncthreads();
        if (tid < VDNUM * 8) {
            const int v = tid >> 3, oct = tid & 7;
            const float* w2 = p.Ws2T + (size_t)oct * 32 * VDNUM + v;
            float a = 0.f;
            #pragma unroll 8
            for (int k = 0; k < 32; ++k) a += hid[oct * 32 + k] * w2[(size_t)k * VDNUM];
            predp[v * 8 + oct] = a;
        }
        __syncthreads();
        if (tid < VDNUM) {
            float a = p.bs2[tid];
            #pragma unroll
            for (int o = 0; o < 8; ++o) a += predp[tid * 8 + o];
            predv[tid] = a;
            if (i == 0) __builtin_nontemporal_store(a, p.outP + ((size_t)b * p.S + s) * VDNUM + tid);
        }
        __syncthreads();
        if (tid == 0) {   // first-occurrence argmax (strict >) — identical in all 4 blocks
            int best = 0; float bv = predv[0];
            for (int v = 1; v < VDNUM; ++v) if (predv[v] > bv) { bv = predv[v]; best = v; }
            chr = best;
        }
        __syncthreads();
    }
}

extern "C" void kernel_launch(void* const* d_in, const int* in_sizes, int n_in,
                              void* d_out, int out_size, void* d_ws, size_t ws_size,
                              hipStream_t stream)
{
    P p;
    p.seqs  = (const int*)  d_in[0];
    p.key   = (const float*)d_in[1];
    p.val   = (const float*)d_in[2];
    p.embed = (const float*)d_in[4];
    p.Wih0  = (const float*)d_in[5];  p.Whh0 = (const float*)d_in[6];
    p.bih0  = (const float*)d_in[7];  p.bhh0 = (const float*)d_in[8];
    p.Wih1  = (const float*)d_in[9];  p.Whh1 = (const float*)d_in[10];
    p.bih1  = (const float*)d_in[11]; p.bhh1 = (const float*)d_in[12];
    p.Wih2  = (const float*)d_in[13]; p.Whh2 = (const float*)d_in[14];
    p.bih2  = (const float*)d_in[15]; p.bhh2 = (const float*)d_in[16];
    p.Wq    = (const float*)d_in[17]; p.bq   = (const float*)d_in[18];
    p.Ws1   = (const float*)d_in[19]; p.bs1  = (const float*)d_in[20];
    p.Ws2   = (const float*)d_in[21]; p.bs2  = (const float*)d_in[22];
    p.h0    = (const float*)d_in[23];
    p.c0    = (const float*)d_in[24];
    p.con   = (const float*)d_in[25];

    const int B = in_sizes[0];                  // 64
    p.T = in_sizes[1] / (B * QDIM);             // 2048
    p.S = in_sizes[3] / B;                      // 220

    // workspace layout (bytes; 16B-aligned)
    char* ws = (char*)d_ws;
    p.W0s   = (unsigned short*)(ws + 0);         //   786,432 B
    p.W1s   = (unsigned short*)(ws + 786432);    // 1,048,576 B
    p.W2s   = (unsigned short*)(ws + 1835008);   // 1,048,576 B
    p.Ws1h  = (unsigned short*)(ws + 2883584);   //   200,704 B
    p.bsum  = (float*)(ws + 3084288);            //    12,288 B
    p.WqT4  = (float*)(ws + 3096576);            //   131,072 B
    p.Ws2T  = (float*)(ws + 3227648);            //    33,792 B
    p.Ep    = (float*)(ws + 3261440);            //   135,168 B
    p.flags = (unsigned*)(ws + 3396608);         //    16,384 B
    p.hx    = (float*)(ws + 3412992);            //   196,608 B
    p.pm    = (float*)(ws + 3609600);            //     1,024 B
    p.pz    = (float*)(ws + 3610624);            //     1,024 B
    p.cp    = (float*)(ws + 3611648);            //   131,072 B
    const size_t kvBytes = (size_t)B * QDIM * p.T * 2;   // 33,554,432 each
    p.keyh  = (unsigned short*)(ws + 3742720);
    p.valh  = (unsigned short*)(ws + 3742720 + kvBytes);
    p.dokv  = (ws_size >= 3742720 + 2 * kvBytes) ? 1 : 0;

    p.outS = (float*)d_out;
    p.outP = p.outS + (size_t)B * p.S * p.T;

    prep<<<1024, 256, 0, stream>>>(p);
    if (p.dokv) speller<true ><<<256, 1024, 0, stream>>>(p);
    else        speller<false><<<256, 1024, 0, stream>>>(p);
}